// Round 7
// baseline (143.134 us; speedup 1.0000x reference)
//
#include <hip/hip_runtime.h>

#define NQ 4096
#define NS 8192
#define DD 256
#define NC 64
#define INFV 1000.0f
#define SST 512  // sperm per-class stride (binomial mean 128, sd ~11 -> +34 sigma)
#define QST 256  // qperm per-class stride (mean 64, sd ~8 -> +24 sigma)

typedef __attribute__((ext_vector_type(8))) __bf16 bf16x8;
typedef __attribute__((ext_vector_type(4))) float floatx4;

__device__ inline unsigned short f2bf(float f) {
    unsigned int u = __builtin_bit_cast(unsigned int, f);
    unsigned int r = (u + 0x7FFFu + ((u >> 16) & 1u)) >> 16;
    return (unsigned short)r;
}

__device__ inline bf16x8 cvt8(const float* p) {
    unsigned short tmp[8];
#pragma unroll
    for (int i = 0; i < 8; ++i) tmp[i] = f2bf(p[i]);
    return *(bf16x8*)tmp;
}

// ---- K1: convert to bf16 + norms + diagonal dot (no atomics) ----
__global__ __launch_bounds__(256) void k_prep(const float* __restrict__ xq,
                                              const float* __restrict__ xs,
                                              unsigned short* __restrict__ xqh,
                                              unsigned short* __restrict__ xsh,
                                              float* __restrict__ nq2,
                                              float* __restrict__ ns2,
                                              float* __restrict__ ldot) {
    int row = blockIdx.x * 4 + (threadIdx.x >> 6);
    int lane = threadIdx.x & 63;
    if (row < NQ) {
        float4 a = ((const float4*)(xq + (size_t)row * DD))[lane];
        float4 b = ((const float4*)(xs + (size_t)row * DD))[lane];
        float s = a.x * a.x + a.y * a.y + a.z * a.z + a.w * a.w;
        float d = a.x * b.x + a.y * b.y + a.z * b.z + a.w * b.w;
        ((ushort4*)(xqh + (size_t)row * DD))[lane] =
            make_ushort4(f2bf(a.x), f2bf(a.y), f2bf(a.z), f2bf(a.w));
#pragma unroll
        for (int off = 32; off; off >>= 1) {
            s += __shfl_xor(s, off, 64);
            d += __shfl_xor(d, off, 64);
        }
        if (lane == 0) { nq2[row] = s; ldot[row] = d; }
    } else {
        int r = row - NQ;
        float4 v = ((const float4*)(xs + (size_t)r * DD))[lane];
        float s = v.x * v.x + v.y * v.y + v.z * v.z + v.w * v.w;
        ((ushort4*)(xsh + (size_t)r * DD))[lane] =
            make_ushort4(f2bf(v.x), f2bf(v.y), f2bf(v.z), f2bf(v.w));
#pragma unroll
        for (int off = 32; off; off >>= 1) s += __shfl_xor(s, off, 64);
        if (lane == 0) ns2[r] = s;
    }
}

// ---- K2: one block per class: compact bucket (ballot-rank, no atomics),
//          write counts, then centroid + Sc in the same block ----
__global__ __launch_bounds__(256) void k_bucket(const int* __restrict__ ys,
                                                const float* __restrict__ xs,
                                                const float* __restrict__ ns2,
                                                int* __restrict__ counts,
                                                int* __restrict__ qcounts,
                                                int* __restrict__ sperm,
                                                int* __restrict__ qperm,
                                                float* __restrict__ mcent,
                                                float* __restrict__ Sc) {
    __shared__ int wcntS[4], wcntQ[4];
    __shared__ int baseS, baseQ;
    __shared__ float red[4][256];
    __shared__ float sred[4];

    const int c = blockIdx.x;
    const int tid = threadIdx.x;
    const int wave = tid >> 6;
    const int lane = tid & 63;

    if (tid == 0) { baseS = 0; baseQ = 0; }
    __syncthreads();

    for (int chunk = 0; chunk < NS / 256; ++chunk) {
        int j = chunk * 256 + tid;
        bool p = (ys[j] == c);
        bool pq = p && (j < NQ);
        unsigned long long mS = __ballot(p);
        unsigned long long mQ = __ballot(pq);
        unsigned long long below = (1ull << lane) - 1ull;
        int rS = __popcll(mS & below);
        int rQ = __popcll(mQ & below);
        if (lane == 0) { wcntS[wave] = __popcll(mS); wcntQ[wave] = __popcll(mQ); }
        __syncthreads();
        int offS = baseS, offQ = baseQ;
        for (int w = 0; w < wave; ++w) { offS += wcntS[w]; offQ += wcntQ[w]; }
        if (p) sperm[c * SST + offS + rS] = j;
        if (pq) qperm[c * QST + offQ + rQ] = j;
        __syncthreads();
        if (tid == 0) {
            baseS += wcntS[0] + wcntS[1] + wcntS[2] + wcntS[3];
            baseQ += wcntQ[0] + wcntQ[1] + wcntQ[2] + wcntQ[3];
        }
        __syncthreads();
    }

    const int mc = baseS;
    if (tid == 0) { counts[c] = mc; qcounts[c] = baseQ; }

    // centroid + Sc (4 row-groups x 64-lane float4 columns)
    float4 acc = make_float4(0.f, 0.f, 0.f, 0.f);
    float sacc = 0.0f;
    for (int idx = wave; idx < mc; idx += 4) {
        int row = sperm[c * SST + idx];
        float4 v = ((const float4*)(xs + (size_t)row * DD))[lane];
        acc.x += v.x; acc.y += v.y; acc.z += v.z; acc.w += v.w;
        if (lane == 0) sacc += ns2[row];
    }
    ((float4*)red[wave])[lane] = acc;
    if (lane == 0) sred[wave] = sacc;
    __syncthreads();
    if (wave == 0) {
        int k0 = lane * 4;
#pragma unroll
        for (int j = 0; j < 4; ++j)
            mcent[(size_t)c * DD + k0 + j] =
                red[0][k0 + j] + red[1][k0 + j] + red[2][k0 + j] + red[3][k0 + j];
        if (lane == 0) Sc[c] = sred[0] + sred[1] + sred[2] + sred[3];
    }
}

// ---- K3: positive logsumexp (class c, 16-query tile per block) ----
__global__ __launch_bounds__(256) void k_pos(const unsigned short* __restrict__ xqh,
                                             const unsigned short* __restrict__ xsh,
                                             const float* __restrict__ nq2,
                                             const float* __restrict__ ns2,
                                             const int* __restrict__ counts,
                                             const int* __restrict__ qcounts,
                                             const int* __restrict__ sperm,
                                             const int* __restrict__ qperm,
                                             float* __restrict__ poslog) {
    __shared__ int qish[16];
    __shared__ float nqsh[16];
    __shared__ float msh[4][16], ssh[4][16];

    const int c = blockIdx.x;
    const int qc = qcounts[c];
    const int mc = counts[c];
    const int sbase = c * SST;
    const int qbase = c * QST;
    const float ov = (mc > 1) ? -INFV : 0.0f;

    const int tid = threadIdx.x;
    const int lane = tid & 63;
    const int wave = tid >> 6;
    const int quad = lane >> 4;
    const int l15 = lane & 15;

    for (int q0 = blockIdx.y * 16; q0 < qc; q0 += 64) {
        __syncthreads();
        if (tid < 16) {
            int idx = q0 + tid;
            int qi = (idx < qc) ? qperm[qbase + idx] : -1;
            qish[tid] = qi;
            nqsh[tid] = (qi >= 0) ? nq2[qi] : 0.0f;
        }
        __syncthreads();

        int qrow = qish[l15];
        int qrowL = qrow < 0 ? 0 : qrow;
        const unsigned short* ap = xqh + (size_t)qrowL * DD + quad * 8;
        bf16x8 afr[8];
#pragma unroll
        for (int ks = 0; ks < 8; ++ks) afr[ks] = *(const bf16x8*)(ap + ks * 32);

        int qid[4];
        float nqr[4];
#pragma unroll
        for (int r = 0; r < 4; ++r) {
            qid[r] = qish[quad * 4 + r];
            nqr[r] = nqsh[quad * 4 + r];
        }

        float mrun[4], srun[4];
#pragma unroll
        for (int r = 0; r < 4; ++r) { mrun[r] = -1e30f; srun[r] = 0.0f; }

        for (int jt = wave * 16; jt < mc; jt += 64) {
            int jcol = jt + l15;
            bool valid = jcol < mc;
            int sj = valid ? sperm[sbase + jcol] : -1;
            int sjL = sj < 0 ? 0 : sj;
            float nsv = valid ? ns2[sjL] : 0.0f;
            const unsigned short* bp = xsh + (size_t)sjL * DD + quad * 8;
            floatx4 acc = (floatx4)0.0f;
#pragma unroll
            for (int ks = 0; ks < 8; ++ks) {
                bf16x8 bfr = *(const bf16x8*)(bp + ks * 32);
                acc = __builtin_amdgcn_mfma_f32_16x16x32_bf16(afr[ks], bfr, acc, 0, 0, 0);
            }
            if (valid) {
#pragma unroll
                for (int r = 0; r < 4; ++r) {
                    float v = fminf(acc[r] - 0.5f * (nqr[r] + nsv), 0.0f);
                    if (sj == qid[r]) v = ov;
                    float mn = fmaxf(mrun[r], v);
                    srun[r] = srun[r] * __expf(mrun[r] - mn) + __expf(v - mn);
                    mrun[r] = mn;
                }
            }
        }
#pragma unroll
        for (int r = 0; r < 4; ++r) {
#pragma unroll
            for (int off = 1; off < 16; off <<= 1) {
                float m2 = __shfl_xor(mrun[r], off, 64);
                float s2 = __shfl_xor(srun[r], off, 64);
                float mn = fmaxf(mrun[r], m2);
                srun[r] = srun[r] * __expf(mrun[r] - mn) + s2 * __expf(m2 - mn);
                mrun[r] = mn;
            }
            if (l15 == 0) {
                msh[wave][quad * 4 + r] = mrun[r];
                ssh[wave][quad * 4 + r] = srun[r];
            }
        }
        __syncthreads();
        if (tid < 16) {
            int qi = qish[tid];
            if (qi >= 0) {
                float m = -1e30f, s = 0.0f;
#pragma unroll
                for (int w = 0; w < 4; ++w) {
                    float mw = msh[w][tid], sw = ssh[w][tid];
                    float mn = fmaxf(m, mw);
                    s = s * __expf(m - mn) + sw * __expf(mw - mn);
                    m = mn;
                }
                poslog[qi] = m + __logf(s);
            }
        }
    }
}

// ---- K4: summed via centroid MFMA + per-row neg logsumexp -> block partials ----
__global__ __launch_bounds__(256) void k_final(const unsigned short* __restrict__ xqh,
                                               const float* __restrict__ mcent,
                                               const float* __restrict__ Sc,
                                               const int* __restrict__ counts,
                                               const int* __restrict__ yq,
                                               const float* __restrict__ nq2,
                                               const float* __restrict__ ns2,
                                               const float* __restrict__ ldot,
                                               const float* __restrict__ poslog,
                                               float* __restrict__ partial) {
    __shared__ float cntf[64], scs[64], nqs[64], ldts[64], ns2s[64], pls[64], red[64];
    __shared__ int ysh[64];

    const int b = blockIdx.x;
    const int tid = threadIdx.x;
    const int lane = tid & 63;
    const int wave = tid >> 6;
    const int quad = lane >> 4;
    const int l15 = lane & 15;

    if (tid < 64) {
        cntf[tid] = (float)counts[tid];
        scs[tid] = Sc[tid];
        int row = b * 64 + tid;
        nqs[tid] = nq2[row];
        ysh[tid] = yq[row];
        ldts[tid] = ldot[row];
        ns2s[tid] = ns2[row];
        pls[tid] = poslog[row];
    }
    __syncthreads();

    const unsigned short* ap = xqh + (size_t)(b * 64 + wave * 16 + l15) * DD + quad * 8;
    bf16x8 afr[8];
#pragma unroll
    for (int ks = 0; ks < 8; ++ks) afr[ks] = *(const bf16x8*)(ap + ks * 32);

    floatx4 acc[4];
#pragma unroll
    for (int n = 0; n < 4; ++n) acc[n] = (floatx4)0.0f;

#pragma unroll
    for (int n = 0; n < 4; ++n) {
        const float* bp = mcent + (size_t)(n * 16 + l15) * DD + quad * 8;
#pragma unroll
        for (int ks = 0; ks < 8; ++ks) {
            bf16x8 bfr = cvt8(bp + ks * 32);
            acc[n] = __builtin_amdgcn_mfma_f32_16x16x32_bf16(afr[ks], bfr, acc[n], 0, 0, 0);
        }
    }

#pragma unroll
    for (int r = 0; r < 4; ++r) {
        int rl = wave * 16 + quad * 4 + r;
        float nqv = nqs[rl];
        int y = ysh[rl];
        float vv[4];
#pragma unroll
        for (int n = 0; n < 4; ++n) {
            int col = n * 16 + l15;
            float cnt = cntf[col];
            float val = acc[n][r] - 0.5f * cnt * nqv - 0.5f * scs[col];
            float sub = (col == y) ? 1.0f : 0.0f;
            if (col == y) {
                float lii = ldts[rl] - 0.5f * (nqv + ns2s[rl]);
                val += ((cnt > 1.5f) ? -INFV : 0.0f) - lii;
            }
            vv[n] = val / (cnt - sub);
        }
        float m = fmaxf(fmaxf(vv[0], vv[1]), fmaxf(vv[2], vv[3]));
#pragma unroll
        for (int off = 1; off < 16; off <<= 1) m = fmaxf(m, __shfl_xor(m, off, 64));
        float e = __expf(vv[0] - m) + __expf(vv[1] - m) + __expf(vv[2] - m) +
                  __expf(vv[3] - m);
#pragma unroll
        for (int off = 1; off < 16; off <<= 1) e += __shfl_xor(e, off, 64);
        if (l15 == 0) red[rl] = (m + __logf(e) - pls[rl]) * (1.0f / (float)NQ);
    }
    __syncthreads();
    if (tid < 64) {
        float s = red[tid];
#pragma unroll
        for (int off = 32; off; off >>= 1) s += __shfl_xor(s, off, 64);
        if (tid == 0) partial[b] = s;
    }
}

// ---- K5: final 64-way sum -> out[0] (direct store, no zeroing needed) ----
__global__ void k_red(const float* __restrict__ partial, float* __restrict__ out) {
    int lane = threadIdx.x;
    float s = partial[lane];
#pragma unroll
    for (int off = 32; off; off >>= 1) s += __shfl_xor(s, off, 64);
    if (lane == 0) out[0] = s;
}

extern "C" void kernel_launch(void* const* d_in, const int* in_sizes, int n_in,
                              void* d_out, int out_size, void* d_ws, size_t ws_size,
                              hipStream_t stream) {
    const float* xq = (const float*)d_in[0];
    const int* yq = (const int*)d_in[1];
    const float* xs = (const float*)d_in[2];
    const int* ys = (const int*)d_in[3];
    float* out = (float*)d_out;
    char* ws = (char*)d_ws;

    unsigned short* xqh = (unsigned short*)(ws + 0);        // 2 MB
    unsigned short* xsh = (unsigned short*)(ws + 2097152);  // 4 MB
    float* nq2 = (float*)(ws + 6291456);     // 16 KB
    float* ns2 = (float*)(ws + 6307840);     // 32 KB
    int* counts = (int*)(ws + 6340608);      // 256 B
    int* qcounts = (int*)(ws + 6340864);     // 256 B
    int* sperm = (int*)(ws + 6341120);       // 64*512*4 = 128 KB
    int* qperm = (int*)(ws + 6472192);       // 64*256*4 = 64 KB
    float* poslog = (float*)(ws + 6537728);  // 16 KB
    float* ldot = (float*)(ws + 6554112);    // 16 KB
    float* mcent = (float*)(ws + 6570496);   // 64 KB fp32 c-major [c*256+k]
    float* Sc = (float*)(ws + 6636032);      // 256 B
    float* partial = (float*)(ws + 6636288); // 256 B

    k_prep<<<dim3((NQ + NS) / 4), dim3(256), 0, stream>>>(xq, xs, xqh, xsh, nq2, ns2,
                                                          ldot);
    k_bucket<<<dim3(NC), dim3(256), 0, stream>>>(ys, xs, ns2, counts, qcounts, sperm,
                                                 qperm, mcent, Sc);
    k_pos<<<dim3(NC, 4), dim3(256), 0, stream>>>(xqh, xsh, nq2, ns2, counts, qcounts,
                                                 sperm, qperm, poslog);
    k_final<<<dim3(64), dim3(256), 0, stream>>>(xqh, mcent, Sc, counts, yq, nq2, ns2,
                                                ldot, poslog, partial);
    k_red<<<dim3(1), dim3(64), 0, stream>>>(partial, out);
}

// Round 8
// 119.183 us; speedup vs baseline: 1.2010x; 1.2010x over previous
//
#include <hip/hip_runtime.h>

#define NQ 4096
#define NS 8192
#define DD 256
#define NC 64
#define INFV 1000.0f
#define SST 512  // sperm per-class stride (binomial mean 128, sd ~11)
#define QST 256  // qperm per-class stride (mean 64, sd ~8)

typedef __attribute__((ext_vector_type(8))) __bf16 bf16x8;
typedef __attribute__((ext_vector_type(4))) float floatx4;

__device__ inline unsigned short f2bf(float f) {
    unsigned int u = __builtin_bit_cast(unsigned int, f);
    unsigned int r = (u + 0x7FFFu + ((u >> 16) & 1u)) >> 16;
    return (unsigned short)r;
}

__device__ inline bf16x8 cvt8(const float* p) {
    unsigned short tmp[8];
#pragma unroll
    for (int i = 0; i < 8; ++i) tmp[i] = f2bf(p[i]);
    return *(bf16x8*)tmp;
}

// ---- K1: bf16 convert + norms + diag dot; block 0 zeroes cursors + out ----
__global__ __launch_bounds__(256) void k_prep(const float* __restrict__ xq,
                                              const float* __restrict__ xs,
                                              unsigned short* __restrict__ xqh,
                                              unsigned short* __restrict__ xsh,
                                              float* __restrict__ nq2,
                                              float* __restrict__ ns2,
                                              float* __restrict__ ldot,
                                              int* __restrict__ scur,
                                              int* __restrict__ qcur,
                                              float* __restrict__ out) {
    if (blockIdx.x == 0) {
        int t = threadIdx.x;
        if (t < NC) { scur[t] = 0; qcur[t] = 0; }
        if (t == NC) out[0] = 0.0f;
    }
    int row = blockIdx.x * 4 + (threadIdx.x >> 6);
    int lane = threadIdx.x & 63;
    if (row < NQ) {
        float4 a = ((const float4*)(xq + (size_t)row * DD))[lane];
        float4 b = ((const float4*)(xs + (size_t)row * DD))[lane];
        float s = a.x * a.x + a.y * a.y + a.z * a.z + a.w * a.w;
        float d = a.x * b.x + a.y * b.y + a.z * b.z + a.w * b.w;
        ((ushort4*)(xqh + (size_t)row * DD))[lane] =
            make_ushort4(f2bf(a.x), f2bf(a.y), f2bf(a.z), f2bf(a.w));
#pragma unroll
        for (int off = 32; off; off >>= 1) {
            s += __shfl_xor(s, off, 64);
            d += __shfl_xor(d, off, 64);
        }
        if (lane == 0) { nq2[row] = s; ldot[row] = d; }
    } else {
        int r = row - NQ;
        float4 v = ((const float4*)(xs + (size_t)r * DD))[lane];
        float s = v.x * v.x + v.y * v.y + v.z * v.z + v.w * v.w;
        ((ushort4*)(xsh + (size_t)r * DD))[lane] =
            make_ushort4(f2bf(v.x), f2bf(v.y), f2bf(v.z), f2bf(v.w));
#pragma unroll
        for (int off = 32; off; off >>= 1) s += __shfl_xor(s, off, 64);
        if (lane == 0) ns2[r] = s;
    }
}

// ---- K2: two-level scatter into fixed-stride buckets; scur/qcur end as counts ----
__global__ __launch_bounds__(256) void k_scat(const int* __restrict__ ys,
                                              int* __restrict__ scur,
                                              int* __restrict__ qcur,
                                              int* __restrict__ sperm,
                                              int* __restrict__ qperm) {
    __shared__ int h[NC], hq[NC], base[NC], baseq[NC], cur[NC], curq[NC];
    const int tid = threadIdx.x;
    if (tid < NC) { h[tid] = 0; hq[tid] = 0; cur[tid] = 0; curq[tid] = 0; }
    __syncthreads();
    const int j = blockIdx.x * 256 + tid;
    const int c = ys[j];
    const bool isq = j < NQ;
    atomicAdd(&h[c], 1);
    if (isq) atomicAdd(&hq[c], 1);
    __syncthreads();
    if (tid < NC) {
        base[tid] = h[tid] ? atomicAdd(&scur[tid], h[tid]) : 0;
        baseq[tid] = hq[tid] ? atomicAdd(&qcur[tid], hq[tid]) : 0;
    }
    __syncthreads();
    int rank = atomicAdd(&cur[c], 1);
    sperm[c * SST + base[c] + rank] = j;
    if (isq) {
        int rq = atomicAdd(&curq[c], 1);
        qperm[c * QST + baseq[c] + rq] = j;
    }
}

// ---- K3: positive logsumexp; y==0 blocks also compute class centroid + Sc ----
__global__ __launch_bounds__(256) void k_pos(const unsigned short* __restrict__ xqh,
                                             const unsigned short* __restrict__ xsh,
                                             const float* __restrict__ xs,
                                             const float* __restrict__ nq2,
                                             const float* __restrict__ ns2,
                                             const int* __restrict__ counts,
                                             const int* __restrict__ qcounts,
                                             const int* __restrict__ sperm,
                                             const int* __restrict__ qperm,
                                             float* __restrict__ mcent,
                                             float* __restrict__ Sc,
                                             float* __restrict__ poslog) {
    __shared__ int qish[16];
    __shared__ float nqsh[16];
    __shared__ float msh[4][16], ssh[4][16];
    __shared__ float red[4][256];
    __shared__ float sred[4];

    const int c = blockIdx.x;
    const int qc = qcounts[c];
    const int mc = counts[c];
    const int sbase = c * SST;
    const int qbase = c * QST;
    const float ov = (mc > 1) ? -INFV : 0.0f;

    const int tid = threadIdx.x;
    const int lane = tid & 63;
    const int wave = tid >> 6;
    const int quad = lane >> 4;
    const int l15 = lane & 15;

    if (blockIdx.y == 0) {
        // centroid + Sc for this class (direct store, no atomics)
        float4 acc = make_float4(0.f, 0.f, 0.f, 0.f);
        float sacc = 0.0f;
        for (int idx = wave; idx < mc; idx += 4) {
            int row = sperm[sbase + idx];
            float4 v = ((const float4*)(xs + (size_t)row * DD))[lane];
            acc.x += v.x; acc.y += v.y; acc.z += v.z; acc.w += v.w;
            if (lane == 0) sacc += ns2[row];
        }
        ((float4*)red[wave])[lane] = acc;
        if (lane == 0) sred[wave] = sacc;
        __syncthreads();
        if (wave == 0) {
            int k0 = lane * 4;
#pragma unroll
            for (int j = 0; j < 4; ++j)
                mcent[(size_t)c * DD + k0 + j] =
                    red[0][k0 + j] + red[1][k0 + j] + red[2][k0 + j] + red[3][k0 + j];
            if (lane == 0) Sc[c] = sred[0] + sred[1] + sred[2] + sred[3];
        }
    }

    for (int q0 = blockIdx.y * 16; q0 < qc; q0 += 64) {
        __syncthreads();
        if (tid < 16) {
            int idx = q0 + tid;
            int qi = (idx < qc) ? qperm[qbase + idx] : -1;
            qish[tid] = qi;
            nqsh[tid] = (qi >= 0) ? nq2[qi] : 0.0f;
        }
        __syncthreads();

        int qrow = qish[l15];
        int qrowL = qrow < 0 ? 0 : qrow;
        const unsigned short* ap = xqh + (size_t)qrowL * DD + quad * 8;
        bf16x8 afr[8];
#pragma unroll
        for (int ks = 0; ks < 8; ++ks) afr[ks] = *(const bf16x8*)(ap + ks * 32);

        int qid[4];
        float nqr[4];
#pragma unroll
        for (int r = 0; r < 4; ++r) {
            qid[r] = qish[quad * 4 + r];
            nqr[r] = nqsh[quad * 4 + r];
        }

        float mrun[4], srun[4];
#pragma unroll
        for (int r = 0; r < 4; ++r) { mrun[r] = -1e30f; srun[r] = 0.0f; }

        for (int jt = wave * 16; jt < mc; jt += 64) {
            int jcol = jt + l15;
            bool valid = jcol < mc;
            int sj = valid ? sperm[sbase + jcol] : -1;
            int sjL = sj < 0 ? 0 : sj;
            float nsv = valid ? ns2[sjL] : 0.0f;
            const unsigned short* bp = xsh + (size_t)sjL * DD + quad * 8;
            floatx4 acc = (floatx4)0.0f;
#pragma unroll
            for (int ks = 0; ks < 8; ++ks) {
                bf16x8 bfr = *(const bf16x8*)(bp + ks * 32);
                acc = __builtin_amdgcn_mfma_f32_16x16x32_bf16(afr[ks], bfr, acc, 0, 0, 0);
            }
            if (valid) {
#pragma unroll
                for (int r = 0; r < 4; ++r) {
                    float v = fminf(acc[r] - 0.5f * (nqr[r] + nsv), 0.0f);
                    if (sj == qid[r]) v = ov;
                    float mn = fmaxf(mrun[r], v);
                    srun[r] = srun[r] * __expf(mrun[r] - mn) + __expf(v - mn);
                    mrun[r] = mn;
                }
            }
        }
#pragma unroll
        for (int r = 0; r < 4; ++r) {
#pragma unroll
            for (int off = 1; off < 16; off <<= 1) {
                float m2 = __shfl_xor(mrun[r], off, 64);
                float s2 = __shfl_xor(srun[r], off, 64);
                float mn = fmaxf(mrun[r], m2);
                srun[r] = srun[r] * __expf(mrun[r] - mn) + s2 * __expf(m2 - mn);
                mrun[r] = mn;
            }
            if (l15 == 0) {
                msh[wave][quad * 4 + r] = mrun[r];
                ssh[wave][quad * 4 + r] = srun[r];
            }
        }
        __syncthreads();
        if (tid < 16) {
            int qi = qish[tid];
            if (qi >= 0) {
                float m = -1e30f, s = 0.0f;
#pragma unroll
                for (int w = 0; w < 4; ++w) {
                    float mw = msh[w][tid], sw = ssh[w][tid];
                    float mn = fmaxf(m, mw);
                    s = s * __expf(m - mn) + sw * __expf(mw - mn);
                    m = mn;
                }
                poslog[qi] = m + __logf(s);
            }
        }
    }
}

// ---- K4: centroid MFMA + per-row neg logsumexp -> atomicAdd into out ----
__global__ __launch_bounds__(256) void k_final(const unsigned short* __restrict__ xqh,
                                               const float* __restrict__ mcent,
                                               const float* __restrict__ Sc,
                                               const int* __restrict__ counts,
                                               const int* __restrict__ yq,
                                               const float* __restrict__ nq2,
                                               const float* __restrict__ ns2,
                                               const float* __restrict__ ldot,
                                               const float* __restrict__ poslog,
                                               float* __restrict__ out) {
    __shared__ float cntf[64], scs[64], nqs[64], ldts[64], ns2s[64], pls[64], red[64];
    __shared__ int ysh[64];

    const int b = blockIdx.x;
    const int tid = threadIdx.x;
    const int lane = tid & 63;
    const int wave = tid >> 6;
    const int quad = lane >> 4;
    const int l15 = lane & 15;

    if (tid < 64) {
        cntf[tid] = (float)counts[tid];
        scs[tid] = Sc[tid];
        int row = b * 64 + tid;
        nqs[tid] = nq2[row];
        ysh[tid] = yq[row];
        ldts[tid] = ldot[row];
        ns2s[tid] = ns2[row];
        pls[tid] = poslog[row];
    }
    __syncthreads();

    const unsigned short* ap = xqh + (size_t)(b * 64 + wave * 16 + l15) * DD + quad * 8;
    bf16x8 afr[8];
#pragma unroll
    for (int ks = 0; ks < 8; ++ks) afr[ks] = *(const bf16x8*)(ap + ks * 32);

    floatx4 acc[4];
#pragma unroll
    for (int n = 0; n < 4; ++n) acc[n] = (floatx4)0.0f;

#pragma unroll
    for (int n = 0; n < 4; ++n) {
        const float* bp = mcent + (size_t)(n * 16 + l15) * DD + quad * 8;
#pragma unroll
        for (int ks = 0; ks < 8; ++ks) {
            bf16x8 bfr = cvt8(bp + ks * 32);
            acc[n] = __builtin_amdgcn_mfma_f32_16x16x32_bf16(afr[ks], bfr, acc[n], 0, 0, 0);
        }
    }

#pragma unroll
    for (int r = 0; r < 4; ++r) {
        int rl = wave * 16 + quad * 4 + r;
        float nqv = nqs[rl];
        int y = ysh[rl];
        float vv[4];
#pragma unroll
        for (int n = 0; n < 4; ++n) {
            int col = n * 16 + l15;
            float cnt = cntf[col];
            float val = acc[n][r] - 0.5f * cnt * nqv - 0.5f * scs[col];
            float sub = (col == y) ? 1.0f : 0.0f;
            if (col == y) {
                float lii = ldts[rl] - 0.5f * (nqv + ns2s[rl]);
                val += ((cnt > 1.5f) ? -INFV : 0.0f) - lii;
            }
            vv[n] = val / (cnt - sub);
        }
        float m = fmaxf(fmaxf(vv[0], vv[1]), fmaxf(vv[2], vv[3]));
#pragma unroll
        for (int off = 1; off < 16; off <<= 1) m = fmaxf(m, __shfl_xor(m, off, 64));
        float e = __expf(vv[0] - m) + __expf(vv[1] - m) + __expf(vv[2] - m) +
                  __expf(vv[3] - m);
#pragma unroll
        for (int off = 1; off < 16; off <<= 1) e += __shfl_xor(e, off, 64);
        if (l15 == 0) red[rl] = (m + __logf(e) - pls[rl]) * (1.0f / (float)NQ);
    }
    __syncthreads();
    if (tid < 64) {
        float s = red[tid];
#pragma unroll
        for (int off = 32; off; off >>= 1) s += __shfl_xor(s, off, 64);
        if (tid == 0) atomicAdd(out, s);
    }
}

extern "C" void kernel_launch(void* const* d_in, const int* in_sizes, int n_in,
                              void* d_out, int out_size, void* d_ws, size_t ws_size,
                              hipStream_t stream) {
    const float* xq = (const float*)d_in[0];
    const int* yq = (const int*)d_in[1];
    const float* xs = (const float*)d_in[2];
    const int* ys = (const int*)d_in[3];
    float* out = (float*)d_out;
    char* ws = (char*)d_ws;

    unsigned short* xqh = (unsigned short*)(ws + 0);        // 2 MB
    unsigned short* xsh = (unsigned short*)(ws + 2097152);  // 4 MB
    float* nq2 = (float*)(ws + 6291456);     // 16 KB
    float* ns2 = (float*)(ws + 6307840);     // 32 KB
    int* scur = (int*)(ws + 6340608);        // 256 B (zeroed by k_prep; ends as counts)
    int* qcur = (int*)(ws + 6340864);        // 256 B (zeroed by k_prep; ends as qcounts)
    int* sperm = (int*)(ws + 6341120);       // 64*512*4 = 128 KB
    int* qperm = (int*)(ws + 6472192);       // 64*256*4 = 64 KB
    float* poslog = (float*)(ws + 6537728);  // 16 KB
    float* ldot = (float*)(ws + 6554112);    // 16 KB
    float* mcent = (float*)(ws + 6570496);   // 64 KB fp32 c-major [c*256+k]
    float* Sc = (float*)(ws + 6636032);      // 256 B

    k_prep<<<dim3((NQ + NS) / 4), dim3(256), 0, stream>>>(xq, xs, xqh, xsh, nq2, ns2,
                                                          ldot, scur, qcur, out);
    k_scat<<<dim3(NS / 256), dim3(256), 0, stream>>>(ys, scur, qcur, sperm, qperm);
    k_pos<<<dim3(NC, 4), dim3(256), 0, stream>>>(xqh, xsh, xs, nq2, ns2, scur, qcur,
                                                 sperm, qperm, mcent, Sc, poslog);
    k_final<<<dim3(64), dim3(256), 0, stream>>>(xqh, mcent, Sc, scur, yq, nq2, ns2,
                                                ldot, poslog, out);
}